// Round 11
// baseline (273.426 us; speedup 1.0000x reference)
//
#include <hip/hip_runtime.h>
#include <math.h>

typedef unsigned long long u64;
typedef unsigned int u32;

#define NB 16
#define SL 1024
#define DIM 16
#define MDIM 16
#define KNN 8
#define CH 64    /* coors hidden */
#define NHID 32  /* node hidden */
#define LN_EPS 1e-5f
#define PST 144  /* P row stride: 4 chunks of 36 (33 units + 3 zero pad) */

// silu via hw exp + hw rcp: 5 VALU vs ~12 for div-based (no -ffast-math here)
__device__ __forceinline__ float silu_f(float x) {
    const float e = __expf(-x);
    return x * __builtin_amdgcn_rcpf(1.0f + e);
}

// ---------------- init: feats/coords copy + fused phi for layer 0 ----------------
__global__ __launch_bounds__(256) void init_kernel(
    const float* __restrict__ coords, const int* __restrict__ residues,
    const float* __restrict__ token_emb, const float* __restrict__ pos_emb,
    const float* __restrict__ w1tp, const float* __restrict__ g_eb1,
    float* __restrict__ coordsA, float* __restrict__ featsA,
    float* __restrict__ Pout)
{
    const int t = blockIdx.x * 256 + threadIdx.x;
    const int node = t >> 2;
    const int part = t & 3;
    const int l = node & (SL - 1);
    const int r = residues[node];
    float f[16];
    {
        const float4* te = (const float4*)(token_emb + (size_t)r * DIM);
        const float4* pe = (const float4*)(pos_emb + (size_t)l * DIM);
#pragma unroll
        for (int q = 0; q < 4; ++q) {
            float4 a = te[q], b4 = pe[q];
            f[4*q+0] = a.x + b4.x; f[4*q+1] = a.y + b4.y;
            f[4*q+2] = a.z + b4.z; f[4*q+3] = a.w + b4.w;
        }
    }
    if (part == 0) {
        float4* fo = (float4*)(featsA + (size_t)node * DIM);
#pragma unroll
        for (int q = 0; q < 4; ++q)
            fo[q] = make_float4(f[4*q], f[4*q+1], f[4*q+2], f[4*q+3]);
        coordsA[node * 3 + 0] = coords[node * 3 + 0];
        coordsA[node * 3 + 1] = coords[node * 3 + 1];
        coordsA[node * 3 + 2] = coords[node * 3 + 2];
    }
    const int ubase = (part & 1) * 33;
    const int wbase = (part < 2) ? 0 : 66;
    float res[36];
    res[33] = 0.f; res[34] = 0.f; res[35] = 0.f;
#pragma unroll
    for (int oo = 0; oo < 33; ++oo) {     // FULL unroll: res[] stays in registers
        const int u = ubase + oo;
        const float* wr = w1tp + (wbase + u) * 16;
        float a0 = (part < 2) ? g_eb1[u] : 0.0f;
        float a1 = 0.f, a2 = 0.f, a3 = 0.f;
#pragma unroll
        for (int c = 0; c < 16; c += 4) {
            a0 = fmaf(f[c + 0], wr[c + 0], a0);
            a1 = fmaf(f[c + 1], wr[c + 1], a1);
            a2 = fmaf(f[c + 2], wr[c + 2], a2);
            a3 = fmaf(f[c + 3], wr[c + 3], a3);
        }
        res[oo] = (a0 + a1) + (a2 + a3);
    }
    float4* op = (float4*)(Pout + (size_t)node * PST + part * 36);
#pragma unroll
    for (int q = 0; q < 9; ++q)
        op[q] = make_float4(res[4*q], res[4*q+1], res[4*q+2], res[4*q+3]);
}

// ---------------- weight transpose/pack ----------------
__global__ __launch_bounds__(256) void pack_kernel(
    const float* __restrict__ ew1, const float* __restrict__ ew2,
    const float* __restrict__ cw1,
    const float* __restrict__ nw1, const float* __restrict__ nw2,
    float* __restrict__ w1tp, float* __restrict__ w1rp, float* __restrict__ w2p,
    float* __restrict__ cw1t, float* __restrict__ nw1t, float* __restrict__ nw2t)
{
    const int stride = gridDim.x * 256;
    const int t0 = blockIdx.x * 256 + threadIdx.x;
    for (int idx = t0; idx < 3 * 132 * 16; idx += stride) {
        int d = idx / (132 * 16); int r = idx - d * 132 * 16; int o = r >> 4; int c = r & 15;
        int u = (o < 66) ? o : (o - 66);
        int cc = (o < 66) ? c : (16 + c);
        w1tp[idx] = ew1[(d * 33 + cc) * 66 + u];
    }
    for (int idx = t0; idx < 3 * 72; idx += stride) {
        int d = idx / 72; int o = idx - d * 72; int hh = o / 36; int uu = o - hh * 36;
        w1rp[idx] = (uu < 33) ? ew1[(d * 33 + 32) * 66 + hh * 33 + uu] : 0.0f;
    }
    for (int idx = t0; idx < 3 * 72 * 16; idx += stride) {
        int d = idx / (72 * 16); int r = idx - d * 72 * 16; int u = r >> 4; int v = r & 15;
        int hh = u / 36; int uu = u - hh * 36;
        w2p[idx] = (uu < 33) ? ew2[(d * 66 + hh * 33 + uu) * 16 + v] : 0.0f;
    }
    for (int idx = t0; idx < 3 * CH * 16; idx += stride) {
        int d = idx / (CH * 16); int r = idx - d * CH * 16; int t = r >> 4; int v = r & 15;
        cw1t[(d * CH + t) * 16 + v] = cw1[(d * 16 + v) * CH + t];
    }
    for (int idx = t0; idx < 3 * NHID * 32; idx += stride) {
        int d = idx / (NHID * 32); int r = idx - d * NHID * 32; int u = r >> 5; int c = r & 31;
        nw1t[(d * NHID + u) * 32 + c] = nw1[(d * 32 + c) * NHID + u];
    }
    for (int idx = t0; idx < 3 * 16 * 32; idx += stride) {
        int d = idx / (16 * 32); int r = idx - d * 16 * 32; int c = r >> 5; int u = r & 31;
        nw2t[(d * 16 + c) * 32 + u] = nw2[(d * 32 + u) * 16 + c];
    }
}

// ---------------- kNN: 32 queries/block, 32x32 slices -> 2 blocks/CU (32 waves) ----------------
// r10 diagnosis: grid=256 meant exactly 1 block/CU (16 waves, 50% occupancy); barrier
// waits + merge tail had nothing to overlap with. Same per-CU arithmetic at 512 blocks
// doubles resident waves to the hw max. Keys are unique u32s (index in low bits) so any
// merge-tree shape yields the identical sorted top-8 -> bitwise-same idxbuf.
// 1e5 sentinel is load-bearing: do NOT length-clamp (r4/r5 failure).
__device__ __forceinline__ void merge8(u32* a, const u32* bb) {
    u32 c[8];
#pragma unroll
    for (int t = 0; t < 8; ++t) c[t] = min(a[t], bb[7 - t]);
#define MCAS(x, y) { u32 mn = min(c[x], c[y]); u32 mx = max(c[x], c[y]); c[x] = mn; c[y] = mx; }
    MCAS(0, 4) MCAS(1, 5) MCAS(2, 6) MCAS(3, 7)
    MCAS(0, 2) MCAS(1, 3) MCAS(4, 6) MCAS(5, 7)
    MCAS(0, 1) MCAS(2, 3) MCAS(4, 5) MCAS(6, 7)
#undef MCAS
#pragma unroll
    for (int t = 0; t < 8; ++t) a[t] = c[t];
}

__global__ __launch_bounds__(1024, 8) void knn_kernel(
    const float* __restrict__ coords, const int* __restrict__ lengths,
    int* __restrict__ idxbuf)
{
    __shared__ __align__(16) float4 s_cand[SL];   // 16 KB (padded xyz)
    __shared__ u32 lists[32][32][9];              // 36 KB, pad 9 vs bank conflicts
    const int tid = threadIdx.x;
    const int b = blockIdx.x >> 5;                // 32 blocks per batch
    const int i0 = (blockIdx.x & 31) << 5;        // 32 queries per block
    const int len = lengths[b];
    const float* cb = coords + (size_t)b * SL * 3;
    for (int idx = tid; idx < SL; idx += 1024) {
        const float* cp = cb + idx * 3;
        s_cand[idx] = make_float4(cp[0], cp[1], cp[2], 0.0f);
    }
    __syncthreads();

    const int wv = tid >> 6;                      // wave 0..15
    const int lane = tid & 63;
    const int q = lane & 31;                      // query within block
    const int s = (wv << 1) | (lane >> 5);        // candidate slice 0..31
    const int i = i0 + q;
    const bool mi = i < len;
    const float4 qi = s_cand[i];
    const float xi = qi.x, yi = qi.y, zi = qi.z;

    u32 lst[8];
#pragma unroll
    for (int t = 0; t < 8; ++t) lst[t] = 0xFFFFFFFFu;

    const int jbase = s << 5;
#pragma unroll 4
    for (int jj = 0; jj < 32; ++jj) {
        const int j = jbase + jj;
        const float4 cj = s_cand[j];
        const float dx = xi - cj.x, dy = yi - cj.y, dz = zi - cj.z;
        const float dist = dx * dx + dy * dy + dz * dz;
        const int dij = j - i;
        const bool pm = mi && (j < len);
        const bool adjx = (dij == 1) | (dij == -1);
        float v = pm ? (adjx ? 0.0f : dist) : 1e5f;
        v = (dij == 0) ? -1.0f : v;
        u32 bits = __float_as_uint(v);
        bits ^= (u32)((int)bits >> 31) | 0x80000000u;
        const u32 key = (bits & 0xFFFFFC00u) | (u32)j;
        // sorted-insert: lst[p] = min(max(key, lst[p-1]), lst[p]) -- 2 VALU/level
#pragma unroll
        for (int p = 7; p >= 1; --p)
            lst[p] = min(max(key, lst[p - 1]), lst[p]);
        lst[0] = min(key, lst[0]);
    }

#pragma unroll
    for (int t = 0; t < 8; ++t) lists[s][q][t] = lst[t];
    __syncthreads();

    if (tid < 512) {
        const int p = tid >> 5, qq = tid & 31;
        u32 a[8], bb[8];
#pragma unroll
        for (int t = 0; t < 8; ++t) { a[t] = lists[2 * p][qq][t]; bb[t] = lists[2 * p + 1][qq][t]; }
        merge8(a, bb);
#pragma unroll
        for (int t = 0; t < 8; ++t) lists[2 * p][qq][t] = a[t];
    }
    __syncthreads();
    if (tid < 256) {
        const int p = tid >> 5, qq = tid & 31;
        u32 a[8], bb[8];
#pragma unroll
        for (int t = 0; t < 8; ++t) { a[t] = lists[4 * p][qq][t]; bb[t] = lists[4 * p + 2][qq][t]; }
        merge8(a, bb);
#pragma unroll
        for (int t = 0; t < 8; ++t) lists[4 * p][qq][t] = a[t];
    }
    __syncthreads();
    if (tid < 128) {
        const int p = tid >> 5, qq = tid & 31;
        u32 a[8], bb[8];
#pragma unroll
        for (int t = 0; t < 8; ++t) { a[t] = lists[8 * p][qq][t]; bb[t] = lists[8 * p + 4][qq][t]; }
        merge8(a, bb);
#pragma unroll
        for (int t = 0; t < 8; ++t) lists[8 * p][qq][t] = a[t];
    }
    __syncthreads();
    if (tid < 64) {
        const int p = tid >> 5, qq = tid & 31;
        u32 a[8], bb[8];
#pragma unroll
        for (int t = 0; t < 8; ++t) { a[t] = lists[16 * p][qq][t]; bb[t] = lists[16 * p + 8][qq][t]; }
        merge8(a, bb);
#pragma unroll
        for (int t = 0; t < 8; ++t) lists[16 * p][qq][t] = a[t];
    }
    __syncthreads();
    if (tid < 32) {
        const int qq = tid;
        u32 a[8], bb[8];
#pragma unroll
        for (int t = 0; t < 8; ++t) { a[t] = lists[0][qq][t]; bb[t] = lists[16][qq][t]; }
        merge8(a, bb);
        const size_t node = (size_t)b * SL + i0 + qq;
        int4 r0 = make_int4((int)(a[0] & 1023u), (int)(a[1] & 1023u), (int)(a[2] & 1023u), (int)(a[3] & 1023u));
        int4 r1 = make_int4((int)(a[4] & 1023u), (int)(a[5] & 1023u), (int)(a[6] & 1023u), (int)(a[7] & 1023u));
        ((int4*)idxbuf)[node * 2 + 0] = r0;
        ((int4*)idxbuf)[node * 2 + 1] = r1;
    }
}

// ---------------- EGNN layer: TWO NODES PER THREAD, liveness-disciplined ----------------
// lane = g(2) | h(1) | k(3): 16 lanes per node-slot, 2 nodes per slot.
__global__ __launch_bounds__(256, 3) void layer_kernel(
    const int d,
    const float* __restrict__ coordsIn, float* __restrict__ coordsOut,
    const float* __restrict__ featsIn, float* __restrict__ featsOut,
    const float* __restrict__ Pbuf,
    const int* __restrict__ idxbuf, const int* __restrict__ lengths,
    const float* __restrict__ w1rp, const float* __restrict__ w2p,
    const float* __restrict__ g_eb2,
    const float* __restrict__ cw1t, const float* __restrict__ g_cb1,
    const float* __restrict__ g_cw2, const float* __restrict__ g_cb2,
    const float* __restrict__ g_lng, const float* __restrict__ g_lnb,
    const float* __restrict__ nw1t, const float* __restrict__ g_nb1,
    const float* __restrict__ nw2t, const float* __restrict__ g_nb2,
    const float* __restrict__ w1tp_all, const float* __restrict__ g_eb1,
    float* __restrict__ PbufOut)
{
    __shared__ float s_w2e[72 * 16];                 // 4608 B
    __shared__ __align__(16) float s_w1r[72];
    __shared__ float s_cw1[CH * 16];                 // 4096 B
    __shared__ float s_cw2v[CH];
    __shared__ float s_nw1[NHID * 36];               // padded rows: bank spread
    __shared__ float s_nw2[16 * 36];
    __shared__ float s_eb2[16], s_cb1[CH];
    __shared__ float s_lng[16], s_lnb[16], s_nb1[32], s_nb2[16];
    __shared__ float s_cb2v;

    const int tid = threadIdx.x;
    for (int t = tid; t < 72 * 16; t += 256) s_w2e[t] = w2p[d * 72 * 16 + t];
    for (int t = tid; t < CH * 16; t += 256) s_cw1[t] = cw1t[d * CH * 16 + t];
    for (int t = tid; t < NHID * 32; t += 256) s_nw1[(t >> 5) * 36 + (t & 31)] = nw1t[d * NHID * 32 + t];
    for (int t = tid; t < 16 * 32; t += 256) s_nw2[(t >> 5) * 36 + (t & 31)] = nw2t[d * 16 * 32 + t];
    if (tid < 72) s_w1r[tid] = w1rp[d * 72 + tid];
    if (tid < CH) { s_cw2v[tid] = g_cw2[d * CH + tid]; s_cb1[tid] = g_cb1[d * CH + tid]; }
    if (tid < 16) {
        s_eb2[tid] = g_eb2[d * 16 + tid];
        s_lng[tid] = g_lng[d * 16 + tid];
        s_lnb[tid] = g_lnb[d * 16 + tid];
        s_nb2[tid] = g_nb2[d * 16 + tid];
    }
    if (tid < 32) s_nb1[tid] = g_nb1[d * 32 + tid];
    if (tid == 0) s_cb2v = g_cb2[d];

    const int lane = tid & 63;
    const int h = (lane >> 3) & 1;               // lane-bit half
    const int k = lane & 7;                      // edge within node
    const int sub = lane & 15;
    const int nA = blockIdx.x * 32 + (tid >> 4); // node A
    const int nB = nA + 16;                      // node B (same batch: 1024%32==0)
    const int b = nA >> 10;
    const int len = lengths[b];
    const int jA = idxbuf[nA * 8 + k];
    const int jB = idxbuf[nB * 8 + k];
    const bool emA = ((nA & 1023) < len) && (jA < len);
    const bool emB = ((nB & 1023) < len) && (jB < len);

    // ---- coords ----
    float ciA[3], relA[3], ciB[3], relB[3];
    {
        const float* cpA = coordsIn + (size_t)nA * 3;
        const float* cqA = coordsIn + ((size_t)b * SL + jA) * 3;
        ciA[0] = cpA[0]; ciA[1] = cpA[1]; ciA[2] = cpA[2];
        relA[0] = ciA[0] - cqA[0]; relA[1] = ciA[1] - cqA[1]; relA[2] = ciA[2] - cqA[2];
        const float* cpB = coordsIn + (size_t)nB * 3;
        const float* cqB = coordsIn + ((size_t)b * SL + jB) * 3;
        ciB[0] = cpB[0]; ciB[1] = cpB[1]; ciB[2] = cpB[2];
        relB[0] = ciB[0] - cqB[0]; relB[1] = ciB[1] - cqB[1]; relB[2] = ciB[2] - cqB[2];
    }
    const float rdA = fmaf(relA[0], relA[0], fmaf(relA[1], relA[1], relA[2] * relA[2]));
    const float rdB = fmaf(relB[0], relB[0], fmaf(relB[1], relB[1], relB[2] * relB[2]));

    const int ub = h * 36;
    const float* PiA = Pbuf + (size_t)nA * PST + ub;
    const float* PjA = Pbuf + ((size_t)b * SL + jA) * PST + 72 + ub;
    const float* PiB = Pbuf + (size_t)nB * PST + ub;
    const float* PjB = Pbuf + ((size_t)b * SL + jB) * PST + 72 + ub;

    __syncthreads();   // weights staged (only barrier in this kernel)

    // ---- edge MLP: layer-1 partials + layer-2 accumulate, weights shared A/B ----
    float maccA[16], maccB[16];
#pragma unroll
    for (int v = 0; v < 16; ++v) {
        const float e0 = h ? 0.0f : s_eb2[v];
        maccA[v] = e0; maccB[v] = e0;
    }
#pragma unroll
    for (int c4 = 0; c4 < 9; ++c4) {
        const float4 paA = *(const float4*)(PiA + 4 * c4);
        const float4 pbA = *(const float4*)(PjA + 4 * c4);
        const float4 paB = *(const float4*)(PiB + 4 * c4);
        const float4 pbB = *(const float4*)(PjB + 4 * c4);
        const int u0 = ub + c4 * 4;
        const float4 w1r4 = *(const float4*)&s_w1r[u0];
        const float huA0 = silu_f(fmaf(rdA, w1r4.x, paA.x + pbA.x));
        const float huA1 = silu_f(fmaf(rdA, w1r4.y, paA.y + pbA.y));
        const float huA2 = silu_f(fmaf(rdA, w1r4.z, paA.z + pbA.z));
        const float huA3 = silu_f(fmaf(rdA, w1r4.w, paA.w + pbA.w));
        const float huB0 = silu_f(fmaf(rdB, w1r4.x, paB.x + pbB.x));
        const float huB1 = silu_f(fmaf(rdB, w1r4.y, paB.y + pbB.y));
        const float huB2 = silu_f(fmaf(rdB, w1r4.z, paB.z + pbB.z));
        const float huB3 = silu_f(fmaf(rdB, w1r4.w, paB.w + pbB.w));
        const float* w2r = &s_w2e[u0 * 16];
#pragma unroll
        for (int v = 0; v < 16; ++v) {
            const float w0 = w2r[v], w1 = w2r[16 + v], w2_ = w2r[32 + v], w3 = w2r[48 + v];
            maccA[v] = fmaf(huA3, w3, fmaf(huA2, w2_, fmaf(huA1, w1, fmaf(huA0, w0, maccA[v]))));
            maccB[v] = fmaf(huB3, w3, fmaf(huB2, w2_, fmaf(huB1, w1, fmaf(huB0, w0, maccB[v]))));
        }
    }

    // ---- combine halves in-wave (partner = lane^8): macc becomes mm IN PLACE ----
#pragma unroll
    for (int v = 0; v < 16; ++v) {
        maccA[v] = silu_f(maccA[v] + __shfl_xor(maccA[v], 8, 64));
        maccB[v] = silu_f(maccB[v] + __shfl_xor(maccB[v], 8, 64));
    }

    // ---- coors MLP, t-range [h*32, h*32+32), weights shared A/B ----
    const int tb = h * 32;
    float waA = 0.f, waB = 0.f;
#pragma unroll 4
    for (int tt = 0; tt < 32; ++tt) {
        const float* cr = &s_cw1[(tb + tt) * 16];
        const float bias = s_cb1[tb + tt];
        float a0A = bias, a1A = 0.f, a0B = bias, a1B = 0.f;
#pragma unroll
        for (int v = 0; v < 16; v += 2) {
            a0A = fmaf(maccA[v], cr[v], a0A);
            a1A = fmaf(maccA[v + 1], cr[v + 1], a1A);
            a0B = fmaf(maccB[v], cr[v], a0B);
            a1B = fmaf(maccB[v + 1], cr[v + 1], a1B);
        }
        const float cw2v = s_cw2v[tb + tt];
        waA = fmaf(silu_f(a0A + a1A), cw2v, waA);
        waB = fmaf(silu_f(a0B + a1B), cw2v, waB);
    }
    const float waoA = __shfl_xor(waA, 8, 64);
    const float waoB = __shfl_xor(waB, 8, 64);
    const float weA = emA ? (waA + waoA + s_cb2v) : 0.f;
    const float weB = emB ? (waB + waoB + s_cb2v) : 0.f;

    // ---- coordinate update: reduce over 8 edges (xor over k bits) ----
    float wr0A = weA * relA[0], wr1A = weA * relA[1], wr2A = weA * relA[2];
    float wr0B = weB * relB[0], wr1B = weB * relB[1], wr2B = weB * relB[2];
#pragma unroll
    for (int s = 1; s < 8; s <<= 1) {
        wr0A += __shfl_xor(wr0A, s, 64);
        wr1A += __shfl_xor(wr1A, s, 64);
        wr2A += __shfl_xor(wr2A, s, 64);
        wr0B += __shfl_xor(wr0B, s, 64);
        wr1B += __shfl_xor(wr1B, s, 64);
        wr2B += __shfl_xor(wr2B, s, 64);
    }
    if ((lane & 15) == 0) {
        coordsOut[(size_t)nA * 3 + 0] = ciA[0] + wr0A;
        coordsOut[(size_t)nA * 3 + 1] = ciA[1] + wr1A;
        coordsOut[(size_t)nA * 3 + 2] = ciA[2] + wr2A;
        coordsOut[(size_t)nB * 3 + 0] = ciB[0] + wr0B;
        coordsOut[(size_t)nB * 3 + 1] = ciB[1] + wr1B;
        coordsOut[(size_t)nB * 3 + 2] = ciB[2] + wr2B;
    }
    // ci/rel dead here.

    // ---- m_i: macc (holding mm) masked + butterfly-reduced IN PLACE ----
#pragma unroll
    for (int v = 0; v < 16; ++v) {
        maccA[v] = emA ? maccA[v] : 0.f;
        maccB[v] = emB ? maccB[v] : 0.f;
#pragma unroll
        for (int s = 1; s < 8; s <<= 1) {
            maccA[v] += __shfl_xor(maccA[v], s, 64);
            maccB[v] += __shfl_xor(maccB[v], s, 64);
        }
    }
    // macc now holds m_i.

    // ---- feats load (deferred: fi live range starts here) ----
    float fiA[16], fiB[16];
    {
        const float4* ppA = (const float4*)(featsIn + (size_t)nA * DIM);
        float4 a0 = ppA[0], a1 = ppA[1], a2 = ppA[2], a3 = ppA[3];
        fiA[0]=a0.x; fiA[1]=a0.y; fiA[2]=a0.z; fiA[3]=a0.w;
        fiA[4]=a1.x; fiA[5]=a1.y; fiA[6]=a1.z; fiA[7]=a1.w;
        fiA[8]=a2.x; fiA[9]=a2.y; fiA[10]=a2.z; fiA[11]=a2.w;
        fiA[12]=a3.x; fiA[13]=a3.y; fiA[14]=a3.z; fiA[15]=a3.w;
        const float4* ppB = (const float4*)(featsIn + (size_t)nB * DIM);
        float4 b0 = ppB[0], b1 = ppB[1], b2 = ppB[2], b3 = ppB[3];
        fiB[0]=b0.x; fiB[1]=b0.y; fiB[2]=b0.z; fiB[3]=b0.w;
        fiB[4]=b1.x; fiB[5]=b1.y; fiB[6]=b1.z; fiB[7]=b1.w;
        fiB[8]=b2.x; fiB[9]=b2.y; fiB[10]=b2.z; fiB[11]=b2.w;
        fiB[12]=b3.x; fiB[13]=b3.y; fiB[14]=b3.z; fiB[15]=b3.w;
    }
    const float fiSubA = featsIn[(size_t)nA * DIM + sub];   // residual channel
    const float fiSubB = featsIn[(size_t)nB * DIM + sub];

    // ---- LayerNorm: fi becomes nn IN PLACE ----
    {
        float mu = 0.f;
#pragma unroll
        for (int c = 0; c < 16; ++c) mu += fiA[c];
        mu *= 0.0625f;
        float var = 0.f;
#pragma unroll
        for (int c = 0; c < 16; ++c) { const float dd = fiA[c] - mu; var = fmaf(dd, dd, var); }
        var *= 0.0625f;
        const float rs = rsqrtf(var + LN_EPS);
#pragma unroll
        for (int c = 0; c < 16; ++c) fiA[c] = fmaf((fiA[c] - mu) * rs, s_lng[c], s_lnb[c]);
    }
    {
        float mu = 0.f;
#pragma unroll
        for (int c = 0; c < 16; ++c) mu += fiB[c];
        mu *= 0.0625f;
        float var = 0.f;
#pragma unroll
        for (int c = 0; c < 16; ++c) { const float dd = fiB[c] - mu; var = fmaf(dd, dd, var); }
        var *= 0.0625f;
        const float rs = rsqrtf(var + LN_EPS);
#pragma unroll
        for (int c = 0; c < 16; ++c) fiB[c] = fmaf((fiB[c] - mu) * rs, s_lng[c], s_lnb[c]);
    }
    // fi now holds nn; macc holds m_i.

    // ---- node MLP hidden: lane owns units sub*2, sub*2+1; weights shared A/B ----
    float nhA[2], nhB[2];
#pragma unroll
    for (int q = 0; q < 2; ++q) {
        const int u = sub * 2 + q;
        const float* nr = &s_nw1[u * 36];
        const float bias = s_nb1[u];
        float a0A = bias, a1A = 0.f, a0B = bias, a1B = 0.f;
#pragma unroll
        for (int c = 0; c < 16; c += 2) {
            a0A = fmaf(fiA[c], nr[c], a0A);
            a1A = fmaf(fiA[c + 1], nr[c + 1], a1A);
            a0B = fmaf(fiB[c], nr[c], a0B);
            a1B = fmaf(fiB[c + 1], nr[c + 1], a1B);
        }
#pragma unroll
        for (int v = 0; v < 16; v += 2) {
            a0A = fmaf(maccA[v], nr[16 + v], a0A);
            a1A = fmaf(maccA[v + 1], nr[16 + v + 1], a1A);
            a0B = fmaf(maccB[v], nr[16 + v], a0B);
            a1B = fmaf(maccB[v + 1], nr[16 + v + 1], a1B);
        }
        nhA[q] = silu_f(a0A + a1A);
        nhB[q] = silu_f(a0B + a1B);
    }
    // fi(nn) and macc(m_i) dead here.

    // ---- node MLP out: lane computes channel sub; weights shared A/B ----
    const int nbase = lane & ~15;
    const float* w2c = &s_nw2[sub * 36];
    float oA = s_nb2[sub], oB = s_nb2[sub];
#pragma unroll
    for (int u = 0; u < 32; ++u) {
        const float w = w2c[u];
        oA = fmaf(__shfl(nhA[u & 1], nbase + (u >> 1), 64), w, oA);
        oB = fmaf(__shfl(nhB[u & 1], nbase + (u >> 1), 64), w, oB);
    }
    const float foA = fiSubA + oA;
    const float foB = fiSubB + oB;
    featsOut[(size_t)nA * DIM + sub] = foA;
    featsOut[(size_t)nB * DIM + sub] = foB;

    // ---- fused phi for layer d+1: weights (global, L1/L2) shared A/B ----
    if (d < 2) {
        float frA[16], frB[16];
#pragma unroll
        for (int c = 0; c < 16; ++c) {
            frA[c] = __shfl(foA, nbase + c, 64);
            frB[c] = __shfl(foB, nbase + c, 64);
        }
        const float* wbase = w1tp_all + (d + 1) * 132 * 16;
        const float* bbase = g_eb1 + (d + 1) * 66;
        float* PoutA = PbufOut + (size_t)nA * PST;
        float* PoutB = PbufOut + (size_t)nB * PST;
#pragma unroll
        for (int q = 0; q < 9; ++q) {
            const int col = sub + (q << 4);
            const int ch = (col >= 108) ? 3 : (col >= 72) ? 2 : (col >= 36) ? 1 : 0;
            const int uu = col - ch * 36;
            const bool valid = uu < 33;
            const int u = ((ch & 1) ? 33 : 0) + uu;
            const int uc = valid ? u : 0;
            const int widx = valid ? ((ch < 2) ? u : 66 + u) : 0;
            const float bias = (valid && ch < 2) ? bbase[uc] : 0.0f;
            float a0A = bias, a1A = 0.f, a2A = 0.f, a3A = 0.f;
            float a0B = bias, a1B = 0.f, a2B = 0.f, a3B = 0.f;
            const float* wr = wbase + widx * 16;
#pragma unroll
            for (int cc = 0; cc < 16; cc += 4) {
                const float w0 = wr[cc + 0], w1 = wr[cc + 1], w2_ = wr[cc + 2], w3 = wr[cc + 3];
                a0A = fmaf(frA[cc + 0], w0, a0A);
                a1A = fmaf(frA[cc + 1], w1, a1A);
                a2A = fmaf(frA[cc + 2], w2_, a2A);
                a3A = fmaf(frA[cc + 3], w3, a3A);
                a0B = fmaf(frB[cc + 0], w0, a0B);
                a1B = fmaf(frB[cc + 1], w1, a1B);
                a2B = fmaf(frB[cc + 2], w2_, a2B);
                a3B = fmaf(frB[cc + 3], w3, a3B);
            }
            PoutA[col] = valid ? ((a0A + a1A) + (a2A + a3A)) : 0.0f;
            PoutB[col] = valid ? ((a0B + a1B) + (a2B + a3B)) : 0.0f;
        }
    }
}

// ---------------- final projection ----------------
__global__ __launch_bounds__(256) void final_kernel(
    const float* __restrict__ feats, const float* __restrict__ fw,
    const float* __restrict__ fb, float* __restrict__ out)
{
    const int nid = blockIdx.x * 256 + threadIdx.x;
    if (nid >= NB * SL) return;
    float f[DIM];
#pragma unroll
    for (int c = 0; c < DIM; ++c) f[c] = feats[nid * DIM + c];
#pragma unroll
    for (int o = 0; o < 3; ++o) {
        float acc = fb[o];
#pragma unroll
        for (int c = 0; c < DIM; ++c) acc = fmaf(f[c], fw[c * 3 + o], acc);
        out[nid * 3 + o] = acc;
    }
}

extern "C" void kernel_launch(void* const* d_in, const int* in_sizes, int n_in,
                              void* d_out, int out_size, void* d_ws, size_t ws_size,
                              hipStream_t stream) {
    const float* coords    = (const float*)d_in[0];
    const int*   residues  = (const int*)d_in[1];
    const int*   lengths   = (const int*)d_in[2];
    const float* token_emb = (const float*)d_in[3];
    const float* pos_emb   = (const float*)d_in[4];
    const float* ew1 = (const float*)d_in[5];
    const float* eb1 = (const float*)d_in[6];
    const float* ew2 = (const float*)d_in[7];
    const float* eb2 = (const float*)d_in[8];
    const float* cw1 = (const float*)d_in[9];
    const float* cb1 = (const float*)d_in[10];
    const float* cw2 = (const float*)d_in[11];
    const float* cb2 = (const float*)d_in[12];
    const float* lng = (const float*)d_in[13];
    const float* lnb = (const float*)d_in[14];
    const float* nw1 = (const float*)d_in[15];
    const float* nb1 = (const float*)d_in[16];
    const float* nw2 = (const float*)d_in[17];
    const float* nb2 = (const float*)d_in[18];
    const float* fw  = (const float*)d_in[19];
    const float* fb  = (const float*)d_in[20];

    float* ws = (float*)d_ws;
    float* coordsA = ws;
    float* coordsB = coordsA + NB * SL * 3;
    float* featsA  = coordsB + NB * SL * 3;
    float* featsB  = featsA + NB * SL * DIM;
    int*   idxbuf  = (int*)(featsB + NB * SL * DIM);
    float* w1tp = (float*)(idxbuf + NB * SL * KNN);     // 3*132*16
    float* w1rp = w1tp + 3 * 132 * 16;                  // 3*72
    float* w2p  = w1rp + 3 * 72;                        // 3*72*16
    float* cw1t = w2p + 3 * 72 * 16;                    // 3*64*16
    float* nw1t = cw1t + 3 * CH * 16;                   // 3*32*32
    float* nw2t = nw1t + 3 * NHID * 32;                 // 3*16*32
    float* PbufA = nw2t + 3 * 16 * 32;                  // 16384*144
    float* PbufB = PbufA + (size_t)NB * SL * PST;       // 16384*144

    pack_kernel<<<32, 256, 0, stream>>>(ew1, ew2, cw1, nw1, nw2, w1tp, w1rp, w2p, cw1t, nw1t, nw2t);
    init_kernel<<<NB * SL * 4 / 256, 256, 0, stream>>>(coords, residues, token_emb, pos_emb,
                                                        w1tp, eb1, coordsA, featsA, PbufA);

    float* cIn = coordsA; float* cOut = coordsB;
    float* fIn = featsA;  float* fOut = featsB;
    float* pIn = PbufA;   float* pOut = PbufB;
    for (int d = 0; d < 3; ++d) {
        knn_kernel<<<NB * SL / 32, 1024, 0, stream>>>(cIn, lengths, idxbuf);
        layer_kernel<<<NB * SL * KNN / 256, 256, 0, stream>>>(d, cIn, cOut, fIn, fOut, pIn, idxbuf, lengths,
            w1rp, w2p, eb2, cw1t, cb1, cw2, cb2, lng, lnb, nw1t, nb1, nw2t, nb2,
            w1tp, eb1, pOut);
        float* t;
        t = cIn; cIn = cOut; cOut = t;
        t = fIn; fIn = fOut; fOut = t;
        t = pIn; pIn = pOut; pOut = t;
    }

    final_kernel<<<NB * SL / 256, 256, 0, stream>>>(fIn, fw, fb, (float*)d_out);
}

// Round 13
// 256.201 us; speedup vs baseline: 1.0672x; 1.0672x over previous
//
#include <hip/hip_runtime.h>
#include <math.h>

typedef unsigned long long u64;
typedef unsigned int u32;

#define NB 16
#define SL 1024
#define DIM 16
#define KNN 8
#define CH 64    /* coors hidden */
#define NHID 32  /* node hidden */
#define LN_EPS 1e-5f
#define PST 144  /* P row stride: 4 chunks of 36 (33 units + 3 zero pad) */

// silu via hw exp + hw rcp: 5 VALU vs ~12 for div-based (no -ffast-math here)
__device__ __forceinline__ float silu_f(float x) {
    const float e = __expf(-x);
    return x * __builtin_amdgcn_rcpf(1.0f + e);
}

// ---------------- init: feats/coords copy + fused phi for layer 0 ----------------
__global__ __launch_bounds__(256) void init_kernel(
    const float* __restrict__ coords, const int* __restrict__ residues,
    const float* __restrict__ token_emb, const float* __restrict__ pos_emb,
    const float* __restrict__ w1tp, const float* __restrict__ g_eb1,
    float* __restrict__ coordsA, float* __restrict__ featsA,
    float* __restrict__ Pout)
{
    const int t = blockIdx.x * 256 + threadIdx.x;
    const int node = t >> 2;
    const int part = t & 3;
    const int l = node & (SL - 1);
    const int r = residues[node];
    float f[16];
    {
        const float4* te = (const float4*)(token_emb + (size_t)r * DIM);
        const float4* pe = (const float4*)(pos_emb + (size_t)l * DIM);
#pragma unroll
        for (int q = 0; q < 4; ++q) {
            float4 a = te[q], b4 = pe[q];
            f[4*q+0] = a.x + b4.x; f[4*q+1] = a.y + b4.y;
            f[4*q+2] = a.z + b4.z; f[4*q+3] = a.w + b4.w;
        }
    }
    if (part == 0) {
        float4* fo = (float4*)(featsA + (size_t)node * DIM);
#pragma unroll
        for (int q = 0; q < 4; ++q)
            fo[q] = make_float4(f[4*q], f[4*q+1], f[4*q+2], f[4*q+3]);
        coordsA[node * 3 + 0] = coords[node * 3 + 0];
        coordsA[node * 3 + 1] = coords[node * 3 + 1];
        coordsA[node * 3 + 2] = coords[node * 3 + 2];
    }
    const int ubase = (part & 1) * 33;
    const int wbase = (part < 2) ? 0 : 66;
    float res[36];
    res[33] = 0.f; res[34] = 0.f; res[35] = 0.f;
#pragma unroll
    for (int oo = 0; oo < 33; ++oo) {     // FULL unroll: res[] stays in registers
        const int u = ubase + oo;
        const float* wr = w1tp + (wbase + u) * 16;
        float a0 = (part < 2) ? g_eb1[u] : 0.0f;
        float a1 = 0.f, a2 = 0.f, a3 = 0.f;
#pragma unroll
        for (int c = 0; c < 16; c += 4) {
            a0 = fmaf(f[c + 0], wr[c + 0], a0);
            a1 = fmaf(f[c + 1], wr[c + 1], a1);
            a2 = fmaf(f[c + 2], wr[c + 2], a2);
            a3 = fmaf(f[c + 3], wr[c + 3], a3);
        }
        res[oo] = (a0 + a1) + (a2 + a3);
    }
    float4* op = (float4*)(Pout + (size_t)node * PST + part * 36);
#pragma unroll
    for (int q = 0; q < 9; ++q)
        op[q] = make_float4(res[4*q], res[4*q+1], res[4*q+2], res[4*q+3]);
}

// ---------------- weight transpose/pack ----------------
__global__ __launch_bounds__(256) void pack_kernel(
    const float* __restrict__ ew1, const float* __restrict__ ew2,
    const float* __restrict__ cw1,
    const float* __restrict__ nw1, const float* __restrict__ nw2,
    float* __restrict__ w1tp, float* __restrict__ w1rp, float* __restrict__ w2p,
    float* __restrict__ cw1t, float* __restrict__ nw1t, float* __restrict__ nw2t)
{
    const int stride = gridDim.x * 256;
    const int t0 = blockIdx.x * 256 + threadIdx.x;
    for (int idx = t0; idx < 3 * 132 * 16; idx += stride) {
        int d = idx / (132 * 16); int r = idx - d * 132 * 16; int o = r >> 4; int c = r & 15;
        int u = (o < 66) ? o : (o - 66);
        int cc = (o < 66) ? c : (16 + c);
        w1tp[idx] = ew1[(d * 33 + cc) * 66 + u];
    }
    for (int idx = t0; idx < 3 * 72; idx += stride) {
        int d = idx / 72; int o = idx - d * 72; int hh = o / 36; int uu = o - hh * 36;
        w1rp[idx] = (uu < 33) ? ew1[(d * 33 + 32) * 66 + hh * 33 + uu] : 0.0f;
    }
    for (int idx = t0; idx < 3 * 72 * 16; idx += stride) {
        int d = idx / (72 * 16); int r = idx - d * 72 * 16; int u = r >> 4; int v = r & 15;
        int hh = u / 36; int uu = u - hh * 36;
        w2p[idx] = (uu < 33) ? ew2[(d * 66 + hh * 33 + uu) * 16 + v] : 0.0f;
    }
    for (int idx = t0; idx < 3 * CH * 16; idx += stride) {
        int d = idx / (CH * 16); int r = idx - d * CH * 16; int t = r >> 4; int v = r & 15;
        cw1t[(d * CH + t) * 16 + v] = cw1[(d * 16 + v) * CH + t];
    }
    for (int idx = t0; idx < 3 * NHID * 32; idx += stride) {
        int d = idx / (NHID * 32); int r = idx - d * NHID * 32; int u = r >> 5; int c = r & 31;
        nw1t[(d * NHID + u) * 32 + c] = nw1[(d * 32 + c) * NHID + u];
    }
    for (int idx = t0; idx < 3 * 16 * 32; idx += stride) {
        int d = idx / (16 * 32); int r = idx - d * 16 * 32; int c = r >> 5; int u = r & 31;
        nw2t[(d * 16 + c) * 32 + u] = nw2[(d * 32 + u) * 16 + c];
    }
}

__device__ __forceinline__ void merge8(u32* a, const u32* bb) {
    u32 c[8];
#pragma unroll
    for (int t = 0; t < 8; ++t) c[t] = min(a[t], bb[7 - t]);
#define MCAS(x, y) { u32 mn = min(c[x], c[y]); u32 mx = max(c[x], c[y]); c[x] = mn; c[y] = mx; }
    MCAS(0, 4) MCAS(1, 5) MCAS(2, 6) MCAS(3, 7)
    MCAS(0, 2) MCAS(1, 3) MCAS(4, 6) MCAS(5, 7)
    MCAS(0, 1) MCAS(2, 3) MCAS(4, 5) MCAS(6, 7)
#undef MCAS
#pragma unroll
    for (int t = 0; t < 8; ++t) a[t] = c[t];
}

// ---------------- FUSED knn+layer for one d: NO grid sync needed ----------------
// Key insight (r12 post-mortem): layer(d) needs idxbuf only for its OWN 32 nodes,
// which the SAME block's knn phase computes (same-L1 global write->read, ordered by
// __syncthreads). All cross-block inputs (coords/feats/P) come from the previous
// LAUNCH. So knn+layer fuse into an ordinary kernel; blocks fully independent.
// Cooperative launch is NOT capture-safe (r12 silent no-op) -- normal launch only.
// 1e5 sentinel is load-bearing: do NOT length-clamp (r4/r5 failure).
__global__ __launch_bounds__(256, 2) void fused_kernel(
    const int d,
    const float* __restrict__ coordsIn, float* __restrict__ coordsOut,
    const float* __restrict__ featsIn, float* __restrict__ featsOut,
    const float* __restrict__ Pbuf, float* __restrict__ PbufOut,
    int* __restrict__ idxbuf, const int* __restrict__ lengths,
    const float* __restrict__ w1rp, const float* __restrict__ w2p,
    const float* __restrict__ g_eb2,
    const float* __restrict__ cw1t, const float* __restrict__ g_cb1,
    const float* __restrict__ g_cw2, const float* __restrict__ g_cb2,
    const float* __restrict__ g_lng, const float* __restrict__ g_lnb,
    const float* __restrict__ nw1t, const float* __restrict__ g_nb1,
    const float* __restrict__ nw2t, const float* __restrict__ g_nb2,
    const float* __restrict__ w1tp_all, const float* __restrict__ g_eb1,
    const float* __restrict__ fw, const float* __restrict__ fb,
    float* __restrict__ gout)
{
    __shared__ __align__(16) char smem[25600];
    const int tid = threadIdx.x;
    const int lane = tid & 63;

    // ================= kNN phase: 32 queries, 8 slices x 128 candidates =================
    {
        float4* s_cand = (float4*)smem;                 // 16384 B
        u32* lst_base  = (u32*)(smem + 16384);          // 8*32*9*4 = 9216 B
        const int bk = blockIdx.x >> 5;                 // batch
        const int i0 = (blockIdx.x & 31) << 5;          // 32 queries/block
        const int len = lengths[bk];
        const float* cb = coordsIn + (size_t)bk * SL * 3;
        for (int idx = tid; idx < SL; idx += 256) {
            const float* cp = cb + idx * 3;
            s_cand[idx] = make_float4(cp[0], cp[1], cp[2], 0.0f);
        }
        __syncthreads();

        const int q = tid & 31;
        const int s = tid >> 5;                          // slice 0..7
        const int i = i0 + q;
        const bool mi = i < len;
        const float4 qi = s_cand[i];
        const float xi = qi.x, yi = qi.y, zi = qi.z;

        u32 lst[8];
#pragma unroll
        for (int t = 0; t < 8; ++t) lst[t] = 0xFFFFFFFFu;

        const int jbase = s << 7;
#pragma unroll 4
        for (int jj = 0; jj < 128; ++jj) {
            const int j = jbase + jj;
            const float4 cj = s_cand[j];
            const float dx = xi - cj.x, dy = yi - cj.y, dz = zi - cj.z;
            const float dist = dx * dx + dy * dy + dz * dz;
            const int dij = j - i;
            const bool pm = mi && (j < len);
            const bool adjx = (dij == 1) | (dij == -1);
            float v = pm ? (adjx ? 0.0f : dist) : 1e5f;
            v = (dij == 0) ? -1.0f : v;
            u32 bits = __float_as_uint(v);
            bits ^= (u32)((int)bits >> 31) | 0x80000000u;
            const u32 key = (bits & 0xFFFFFC00u) | (u32)j;
#pragma unroll
            for (int p = 7; p >= 1; --p)
                lst[p] = min(max(key, lst[p - 1]), lst[p]);
            lst[0] = min(key, lst[0]);
        }
#pragma unroll
        for (int t = 0; t < 8; ++t) lst_base[(s * 32 + q) * 9 + t] = lst[t];
        __syncthreads();

        if (tid < 128) {
            const int p = tid >> 5, qq = tid & 31;
            u32 a[8], bb[8];
#pragma unroll
            for (int t = 0; t < 8; ++t) {
                a[t]  = lst_base[((2 * p) * 32 + qq) * 9 + t];
                bb[t] = lst_base[((2 * p + 1) * 32 + qq) * 9 + t];
            }
            merge8(a, bb);
#pragma unroll
            for (int t = 0; t < 8; ++t) lst_base[((2 * p) * 32 + qq) * 9 + t] = a[t];
        }
        __syncthreads();
        if (tid < 64) {
            const int p = tid >> 5, qq = tid & 31;
            u32 a[8], bb[8];
#pragma unroll
            for (int t = 0; t < 8; ++t) {
                a[t]  = lst_base[((4 * p) * 32 + qq) * 9 + t];
                bb[t] = lst_base[((4 * p + 2) * 32 + qq) * 9 + t];
            }
            merge8(a, bb);
#pragma unroll
            for (int t = 0; t < 8; ++t) lst_base[((4 * p) * 32 + qq) * 9 + t] = a[t];
        }
        __syncthreads();
        if (tid < 32) {
            const int qq = tid;
            u32 a[8], bb[8];
#pragma unroll
            for (int t = 0; t < 8; ++t) {
                a[t]  = lst_base[(0 * 32 + qq) * 9 + t];
                bb[t] = lst_base[(4 * 32 + qq) * 9 + t];
            }
            merge8(a, bb);
            const size_t node = (size_t)bk * SL + i0 + qq;
            int4 r0 = make_int4((int)(a[0] & 1023u), (int)(a[1] & 1023u), (int)(a[2] & 1023u), (int)(a[3] & 1023u));
            int4 r1 = make_int4((int)(a[4] & 1023u), (int)(a[5] & 1023u), (int)(a[6] & 1023u), (int)(a[7] & 1023u));
            ((int4*)idxbuf)[node * 2 + 0] = r0;
            ((int4*)idxbuf)[node * 2 + 1] = r1;
        }
    }
    __syncthreads();   // knn LDS readers done; idxbuf rows for this block visible (same L1)

    // ================= layer phase (r10 body; two nodes per thread) =================
    {
        float* s_w2e  = (float*)(smem);
        float* s_cw1  = (float*)(smem + 4608);
        float* s_nw1  = (float*)(smem + 8704);
        float* s_nw2  = (float*)(smem + 13312);
        float* s_w1r  = (float*)(smem + 15616);
        float* s_cw2v = (float*)(smem + 15904);
        float* s_cb1  = (float*)(smem + 16160);
        float* s_eb2  = (float*)(smem + 16416);
        float* s_lng  = (float*)(smem + 16480);
        float* s_lnb  = (float*)(smem + 16544);
        float* s_nb1  = (float*)(smem + 16608);
        float* s_nb2  = (float*)(smem + 16736);
        float* s_cb2  = (float*)(smem + 16800);

        for (int t = tid; t < 72 * 16; t += 256) s_w2e[t] = w2p[d * 72 * 16 + t];
        for (int t = tid; t < CH * 16; t += 256) s_cw1[t] = cw1t[d * CH * 16 + t];
        for (int t = tid; t < NHID * 32; t += 256) s_nw1[(t >> 5) * 36 + (t & 31)] = nw1t[d * NHID * 32 + t];
        for (int t = tid; t < 16 * 32; t += 256) s_nw2[(t >> 5) * 36 + (t & 31)] = nw2t[d * 16 * 32 + t];
        if (tid < 72) s_w1r[tid] = w1rp[d * 72 + tid];
        if (tid < CH) { s_cw2v[tid] = g_cw2[d * CH + tid]; s_cb1[tid] = g_cb1[d * CH + tid]; }
        if (tid < 16) {
            s_eb2[tid] = g_eb2[d * 16 + tid];
            s_lng[tid] = g_lng[d * 16 + tid];
            s_lnb[tid] = g_lnb[d * 16 + tid];
            s_nb2[tid] = g_nb2[d * 16 + tid];
        }
        if (tid < 32) s_nb1[tid] = g_nb1[d * 32 + tid];
        if (tid == 0) s_cb2[0] = g_cb2[d];

        const int h = (lane >> 3) & 1;
        const int k = lane & 7;
        const int sub = lane & 15;
        const int nA = blockIdx.x * 32 + (tid >> 4);
        const int nB = nA + 16;
        const int b = nA >> 10;
        const int len = lengths[b];
        const int jA = idxbuf[nA * 8 + k];
        const int jB = idxbuf[nB * 8 + k];
        const bool emA = ((nA & 1023) < len) && (jA < len);
        const bool emB = ((nB & 1023) < len) && (jB < len);

        float ciA[3], relA[3], ciB[3], relB[3];
        {
            const float* cpA = coordsIn + (size_t)nA * 3;
            const float* cqA = coordsIn + ((size_t)b * SL + jA) * 3;
            ciA[0] = cpA[0]; ciA[1] = cpA[1]; ciA[2] = cpA[2];
            relA[0] = ciA[0] - cqA[0]; relA[1] = ciA[1] - cqA[1]; relA[2] = ciA[2] - cqA[2];
            const float* cpB = coordsIn + (size_t)nB * 3;
            const float* cqB = coordsIn + ((size_t)b * SL + jB) * 3;
            ciB[0] = cpB[0]; ciB[1] = cpB[1]; ciB[2] = cpB[2];
            relB[0] = ciB[0] - cqB[0]; relB[1] = ciB[1] - cqB[1]; relB[2] = ciB[2] - cqB[2];
        }
        const float rdA = fmaf(relA[0], relA[0], fmaf(relA[1], relA[1], relA[2] * relA[2]));
        const float rdB = fmaf(relB[0], relB[0], fmaf(relB[1], relB[1], relB[2] * relB[2]));

        const int ub = h * 36;
        const float* PiA = Pbuf + (size_t)nA * PST + ub;
        const float* PjA = Pbuf + ((size_t)b * SL + jA) * PST + 72 + ub;
        const float* PiB = Pbuf + (size_t)nB * PST + ub;
        const float* PjB = Pbuf + ((size_t)b * SL + jB) * PST + 72 + ub;

        __syncthreads();   // weights staged

        float maccA[16], maccB[16];
#pragma unroll
        for (int v = 0; v < 16; ++v) {
            const float e0 = h ? 0.0f : s_eb2[v];
            maccA[v] = e0; maccB[v] = e0;
        }
#pragma unroll
        for (int c4 = 0; c4 < 9; ++c4) {
            const float4 paA = *(const float4*)(PiA + 4 * c4);
            const float4 pbA = *(const float4*)(PjA + 4 * c4);
            const float4 paB = *(const float4*)(PiB + 4 * c4);
            const float4 pbB = *(const float4*)(PjB + 4 * c4);
            const int u0 = ub + c4 * 4;
            const float4 w1r4 = *(const float4*)&s_w1r[u0];
            const float huA0 = silu_f(fmaf(rdA, w1r4.x, paA.x + pbA.x));
            const float huA1 = silu_f(fmaf(rdA, w1r4.y, paA.y + pbA.y));
            const float huA2 = silu_f(fmaf(rdA, w1r4.z, paA.z + pbA.z));
            const float huA3 = silu_f(fmaf(rdA, w1r4.w, paA.w + pbA.w));
            const float huB0 = silu_f(fmaf(rdB, w1r4.x, paB.x + pbB.x));
            const float huB1 = silu_f(fmaf(rdB, w1r4.y, paB.y + pbB.y));
            const float huB2 = silu_f(fmaf(rdB, w1r4.z, paB.z + pbB.z));
            const float huB3 = silu_f(fmaf(rdB, w1r4.w, paB.w + pbB.w));
            const float* w2r = &s_w2e[u0 * 16];
#pragma unroll
            for (int v = 0; v < 16; ++v) {
                const float w0 = w2r[v], w1 = w2r[16 + v], w2_ = w2r[32 + v], w3 = w2r[48 + v];
                maccA[v] = fmaf(huA3, w3, fmaf(huA2, w2_, fmaf(huA1, w1, fmaf(huA0, w0, maccA[v]))));
                maccB[v] = fmaf(huB3, w3, fmaf(huB2, w2_, fmaf(huB1, w1, fmaf(huB0, w0, maccB[v]))));
            }
        }

#pragma unroll
        for (int v = 0; v < 16; ++v) {
            maccA[v] = silu_f(maccA[v] + __shfl_xor(maccA[v], 8, 64));
            maccB[v] = silu_f(maccB[v] + __shfl_xor(maccB[v], 8, 64));
        }

        const int tb = h * 32;
        float waA = 0.f, waB = 0.f;
#pragma unroll 4
        for (int tt = 0; tt < 32; ++tt) {
            const float* cr = &s_cw1[(tb + tt) * 16];
            const float bias = s_cb1[tb + tt];
            float a0A = bias, a1A = 0.f, a0B = bias, a1B = 0.f;
#pragma unroll
            for (int v = 0; v < 16; v += 2) {
                a0A = fmaf(maccA[v], cr[v], a0A);
                a1A = fmaf(maccA[v + 1], cr[v + 1], a1A);
                a0B = fmaf(maccB[v], cr[v], a0B);
                a1B = fmaf(maccB[v + 1], cr[v + 1], a1B);
            }
            const float cw2v = s_cw2v[tb + tt];
            waA = fmaf(silu_f(a0A + a1A), cw2v, waA);
            waB = fmaf(silu_f(a0B + a1B), cw2v, waB);
        }
        const float waoA = __shfl_xor(waA, 8, 64);
        const float waoB = __shfl_xor(waB, 8, 64);
        const float weA = emA ? (waA + waoA + s_cb2[0]) : 0.f;
        const float weB = emB ? (waB + waoB + s_cb2[0]) : 0.f;

        float wr0A = weA * relA[0], wr1A = weA * relA[1], wr2A = weA * relA[2];
        float wr0B = weB * relB[0], wr1B = weB * relB[1], wr2B = weB * relB[2];
#pragma unroll
        for (int s = 1; s < 8; s <<= 1) {
            wr0A += __shfl_xor(wr0A, s, 64);
            wr1A += __shfl_xor(wr1A, s, 64);
            wr2A += __shfl_xor(wr2A, s, 64);
            wr0B += __shfl_xor(wr0B, s, 64);
            wr1B += __shfl_xor(wr1B, s, 64);
            wr2B += __shfl_xor(wr2B, s, 64);
        }
        if ((lane & 15) == 0) {
            coordsOut[(size_t)nA * 3 + 0] = ciA[0] + wr0A;
            coordsOut[(size_t)nA * 3 + 1] = ciA[1] + wr1A;
            coordsOut[(size_t)nA * 3 + 2] = ciA[2] + wr2A;
            coordsOut[(size_t)nB * 3 + 0] = ciB[0] + wr0B;
            coordsOut[(size_t)nB * 3 + 1] = ciB[1] + wr1B;
            coordsOut[(size_t)nB * 3 + 2] = ciB[2] + wr2B;
        }

#pragma unroll
        for (int v = 0; v < 16; ++v) {
            maccA[v] = emA ? maccA[v] : 0.f;
            maccB[v] = emB ? maccB[v] : 0.f;
#pragma unroll
            for (int s = 1; s < 8; s <<= 1) {
                maccA[v] += __shfl_xor(maccA[v], s, 64);
                maccB[v] += __shfl_xor(maccB[v], s, 64);
            }
        }
        // macc now holds m_i.

        float fiA[16], fiB[16];
        {
            const float4* ppA = (const float4*)(featsIn + (size_t)nA * DIM);
            float4 a0 = ppA[0], a1 = ppA[1], a2 = ppA[2], a3 = ppA[3];
            fiA[0]=a0.x; fiA[1]=a0.y; fiA[2]=a0.z; fiA[3]=a0.w;
            fiA[4]=a1.x; fiA[5]=a1.y; fiA[6]=a1.z; fiA[7]=a1.w;
            fiA[8]=a2.x; fiA[9]=a2.y; fiA[10]=a2.z; fiA[11]=a2.w;
            fiA[12]=a3.x; fiA[13]=a3.y; fiA[14]=a3.z; fiA[15]=a3.w;
            const float4* ppB = (const float4*)(featsIn + (size_t)nB * DIM);
            float4 b0 = ppB[0], b1 = ppB[1], b2 = ppB[2], b3 = ppB[3];
            fiB[0]=b0.x; fiB[1]=b0.y; fiB[2]=b0.z; fiB[3]=b0.w;
            fiB[4]=b1.x; fiB[5]=b1.y; fiB[6]=b1.z; fiB[7]=b1.w;
            fiB[8]=b2.x; fiB[9]=b2.y; fiB[10]=b2.z; fiB[11]=b2.w;
            fiB[12]=b3.x; fiB[13]=b3.y; fiB[14]=b3.z; fiB[15]=b3.w;
        }
        const float fiSubA = featsIn[(size_t)nA * DIM + sub];
        const float fiSubB = featsIn[(size_t)nB * DIM + sub];

        {
            float mu = 0.f;
#pragma unroll
            for (int c = 0; c < 16; ++c) mu += fiA[c];
            mu *= 0.0625f;
            float var = 0.f;
#pragma unroll
            for (int c = 0; c < 16; ++c) { const float dd = fiA[c] - mu; var = fmaf(dd, dd, var); }
            var *= 0.0625f;
            const float rs = rsqrtf(var + LN_EPS);
#pragma unroll
            for (int c = 0; c < 16; ++c) fiA[c] = fmaf((fiA[c] - mu) * rs, s_lng[c], s_lnb[c]);
        }
        {
            float mu = 0.f;
#pragma unroll
            for (int c = 0; c < 16; ++c) mu += fiB[c];
            mu *= 0.0625f;
            float var = 0.f;
#pragma unroll
            for (int c = 0; c < 16; ++c) { const float dd = fiB[c] - mu; var = fmaf(dd, dd, var); }
            var *= 0.0625f;
            const float rs = rsqrtf(var + LN_EPS);
#pragma unroll
            for (int c = 0; c < 16; ++c) fiB[c] = fmaf((fiB[c] - mu) * rs, s_lng[c], s_lnb[c]);
        }

        float nhA[2], nhB[2];
#pragma unroll
        for (int q2 = 0; q2 < 2; ++q2) {
            const int u = sub * 2 + q2;
            const float* nr = &s_nw1[u * 36];
            const float bias = s_nb1[u];
            float a0A = bias, a1A = 0.f, a0B = bias, a1B = 0.f;
#pragma unroll
            for (int c = 0; c < 16; c += 2) {
                a0A = fmaf(fiA[c], nr[c], a0A);
                a1A = fmaf(fiA[c + 1], nr[c + 1], a1A);
                a0B = fmaf(fiB[c], nr[c], a0B);
                a1B = fmaf(fiB[c + 1], nr[c + 1], a1B);
            }
#pragma unroll
            for (int v = 0; v < 16; v += 2) {
                a0A = fmaf(maccA[v], nr[16 + v], a0A);
                a1A = fmaf(maccA[v + 1], nr[16 + v + 1], a1A);
                a0B = fmaf(maccB[v], nr[16 + v], a0B);
                a1B = fmaf(maccB[v + 1], nr[16 + v + 1], a1B);
            }
            nhA[q2] = silu_f(a0A + a1A);
            nhB[q2] = silu_f(a0B + a1B);
        }

        const int nbase = lane & ~15;
        const float* w2c = &s_nw2[sub * 36];
        float oA = s_nb2[sub], oB = s_nb2[sub];
#pragma unroll
        for (int u = 0; u < 32; ++u) {
            const float w = w2c[u];
            oA = fmaf(__shfl(nhA[u & 1], nbase + (u >> 1), 64), w, oA);
            oB = fmaf(__shfl(nhB[u & 1], nbase + (u >> 1), 64), w, oB);
        }
        const float foA = fiSubA + oA;
        const float foB = fiSubB + oB;
        featsOut[(size_t)nA * DIM + sub] = foA;
        featsOut[(size_t)nB * DIM + sub] = foB;

        // gather new feats rows (phi for d<2; final for d==2)
        float frA[16], frB[16];
#pragma unroll
        for (int c = 0; c < 16; ++c) {
            frA[c] = __shfl(foA, nbase + c, 64);
            frB[c] = __shfl(foB, nbase + c, 64);
        }

        if (d < 2) {
            const float* wbase = w1tp_all + (d + 1) * 132 * 16;
            const float* bbase = g_eb1 + (d + 1) * 66;
            float* PoutA = PbufOut + (size_t)nA * PST;
            float* PoutB = PbufOut + (size_t)nB * PST;
#pragma unroll
            for (int q2 = 0; q2 < 9; ++q2) {
                const int col = sub + (q2 << 4);
                const int ch = (col >= 108) ? 3 : (col >= 72) ? 2 : (col >= 36) ? 1 : 0;
                const int uu = col - ch * 36;
                const bool valid = uu < 33;
                const int u = ((ch & 1) ? 33 : 0) + uu;
                const int uc = valid ? u : 0;
                const int widx = valid ? ((ch < 2) ? u : 66 + u) : 0;
                const float bias = (valid && ch < 2) ? bbase[uc] : 0.0f;
                float a0A = bias, a1A = 0.f, a2A = 0.f, a3A = 0.f;
                float a0B = bias, a1B = 0.f, a2B = 0.f, a3B = 0.f;
                const float* wr = wbase + widx * 16;
#pragma unroll
                for (int cc = 0; cc < 16; cc += 4) {
                    const float w0 = wr[cc + 0], w1 = wr[cc + 1], w2_ = wr[cc + 2], w3 = wr[cc + 3];
                    a0A = fmaf(frA[cc + 0], w0, a0A);
                    a1A = fmaf(frA[cc + 1], w1, a1A);
                    a2A = fmaf(frA[cc + 2], w2_, a2A);
                    a3A = fmaf(frA[cc + 3], w3, a3A);
                    a0B = fmaf(frB[cc + 0], w0, a0B);
                    a1B = fmaf(frB[cc + 1], w1, a1B);
                    a2B = fmaf(frB[cc + 2], w2_, a2B);
                    a3B = fmaf(frB[cc + 3], w3, a3B);
                }
                PoutA[col] = valid ? ((a0A + a1A) + (a2A + a3A)) : 0.0f;
                PoutB[col] = valid ? ((a0B + a1B) + (a2B + a3B)) : 0.0f;
            }
        } else {
            // fused final projection: lanes sub<3 compute output channel sub
            if (sub < 3) {
                float accA = fb[sub], accB = fb[sub];
#pragma unroll
                for (int c = 0; c < 16; ++c) {
                    accA = fmaf(frA[c], fw[c * 3 + sub], accA);
                    accB = fmaf(frB[c], fw[c * 3 + sub], accB);
                }
                gout[(size_t)nA * 3 + sub] = accA;
                gout[(size_t)nB * 3 + sub] = accB;
            }
        }
    }
}

extern "C" void kernel_launch(void* const* d_in, const int* in_sizes, int n_in,
                              void* d_out, int out_size, void* d_ws, size_t ws_size,
                              hipStream_t stream) {
    const float* coords    = (const float*)d_in[0];
    const int*   residues  = (const int*)d_in[1];
    const int*   lengths   = (const int*)d_in[2];
    const float* token_emb = (const float*)d_in[3];
    const float* pos_emb   = (const float*)d_in[4];
    const float* ew1 = (const float*)d_in[5];
    const float* eb1 = (const float*)d_in[6];
    const float* ew2 = (const float*)d_in[7];
    const float* eb2 = (const float*)d_in[8];
    const float* cw1 = (const float*)d_in[9];
    const float* cb1 = (const float*)d_in[10];
    const float* cw2 = (const float*)d_in[11];
    const float* cb2 = (const float*)d_in[12];
    const float* lng = (const float*)d_in[13];
    const float* lnb = (const float*)d_in[14];
    const float* nw1 = (const float*)d_in[15];
    const float* nb1 = (const float*)d_in[16];
    const float* nw2 = (const float*)d_in[17];
    const float* nb2 = (const float*)d_in[18];
    const float* fw  = (const float*)d_in[19];
    const float* fb  = (const float*)d_in[20];

    float* ws = (float*)d_ws;
    float* coordsA = ws;
    float* coordsB = coordsA + NB * SL * 3;
    float* featsA  = coordsB + NB * SL * 3;
    float* featsB  = featsA + NB * SL * DIM;
    int*   idxbuf  = (int*)(featsB + NB * SL * DIM);
    float* w1tp = (float*)(idxbuf + NB * SL * KNN);     // 3*132*16
    float* w1rp = w1tp + 3 * 132 * 16;                  // 3*72
    float* w2p  = w1rp + 3 * 72;                        // 3*72*16
    float* cw1t = w2p + 3 * 72 * 16;                    // 3*64*16
    float* nw1t = cw1t + 3 * CH * 16;                   // 3*32*32
    float* nw2t = nw1t + 3 * NHID * 32;                 // 3*16*32
    float* PbufA = nw2t + 3 * 16 * 32;                  // 16384*144
    float* PbufB = PbufA + (size_t)NB * SL * PST;       // 16384*144
    float* gout  = (float*)d_out;

    pack_kernel<<<32, 256, 0, stream>>>(ew1, ew2, cw1, nw1, nw2, w1tp, w1rp, w2p, cw1t, nw1t, nw2t);
    init_kernel<<<NB * SL * 4 / 256, 256, 0, stream>>>(coords, residues, token_emb, pos_emb,
                                                        w1tp, eb1, coordsA, featsA, PbufA);

    float* cIn = coordsA; float* cOut = coordsB;
    float* fIn = featsA;  float* fOut = featsB;
    float* pIn = PbufA;   float* pOut = PbufB;
    for (int d = 0; d < 3; ++d) {
        fused_kernel<<<NB * SL / 32, 256, 0, stream>>>(d, cIn, cOut, fIn, fOut, pIn, pOut,
            idxbuf, lengths,
            w1rp, w2p, eb2, cw1t, cb1, cw2, cb2, lng, lnb, nw1t, nb1, nw2t, nb2,
            w1tp, eb1, fw, fb, gout);
        float* t;
        t = cIn; cIn = cOut; cOut = t;
        t = fIn; fIn = fOut; fOut = t;
        t = pIn; pIn = pOut; pOut = t;
    }
}

// Round 14
// 247.957 us; speedup vs baseline: 1.1027x; 1.0332x over previous
//
#include <hip/hip_runtime.h>
#include <math.h>

typedef unsigned long long u64;
typedef unsigned int u32;

#define NB 16
#define SL 1024
#define DIM 16
#define KNN 8
#define CH 64    /* coors hidden */
#define NHID 32  /* node hidden */
#define LN_EPS 1e-5f
#define PST 144  /* P row stride: 4 chunks of 36 (33 units + 3 zero pad) */

// silu via hw exp + hw rcp: 5 VALU vs ~12 for div-based (no -ffast-math here)
__device__ __forceinline__ float silu_f(float x) {
    const float e = __expf(-x);
    return x * __builtin_amdgcn_rcpf(1.0f + e);
}

// ---------------- init: feats/coords copy + fused phi for layer 0 ----------------
__global__ __launch_bounds__(256) void init_kernel(
    const float* __restrict__ coords, const int* __restrict__ residues,
    const float* __restrict__ token_emb, const float* __restrict__ pos_emb,
    const float* __restrict__ w1tp, const float* __restrict__ g_eb1,
    float* __restrict__ coordsA, float* __restrict__ featsA,
    float* __restrict__ Pout)
{
    const int t = blockIdx.x * 256 + threadIdx.x;
    const int node = t >> 2;
    const int part = t & 3;
    const int l = node & (SL - 1);
    const int r = residues[node];
    float f[16];
    {
        const float4* te = (const float4*)(token_emb + (size_t)r * DIM);
        const float4* pe = (const float4*)(pos_emb + (size_t)l * DIM);
#pragma unroll
        for (int q = 0; q < 4; ++q) {
            float4 a = te[q], b4 = pe[q];
            f[4*q+0] = a.x + b4.x; f[4*q+1] = a.y + b4.y;
            f[4*q+2] = a.z + b4.z; f[4*q+3] = a.w + b4.w;
        }
    }
    if (part == 0) {
        float4* fo = (float4*)(featsA + (size_t)node * DIM);
#pragma unroll
        for (int q = 0; q < 4; ++q)
            fo[q] = make_float4(f[4*q], f[4*q+1], f[4*q+2], f[4*q+3]);
        coordsA[node * 3 + 0] = coords[node * 3 + 0];
        coordsA[node * 3 + 1] = coords[node * 3 + 1];
        coordsA[node * 3 + 2] = coords[node * 3 + 2];
    }
    const int ubase = (part & 1) * 33;
    const int wbase = (part < 2) ? 0 : 66;
    float res[36];
    res[33] = 0.f; res[34] = 0.f; res[35] = 0.f;
#pragma unroll
    for (int oo = 0; oo < 33; ++oo) {     // FULL unroll: res[] stays in registers
        const int u = ubase + oo;
        const float* wr = w1tp + (wbase + u) * 16;
        float a0 = (part < 2) ? g_eb1[u] : 0.0f;
        float a1 = 0.f, a2 = 0.f, a3 = 0.f;
#pragma unroll
        for (int c = 0; c < 16; c += 4) {
            a0 = fmaf(f[c + 0], wr[c + 0], a0);
            a1 = fmaf(f[c + 1], wr[c + 1], a1);
            a2 = fmaf(f[c + 2], wr[c + 2], a2);
            a3 = fmaf(f[c + 3], wr[c + 3], a3);
        }
        res[oo] = (a0 + a1) + (a2 + a3);
    }
    float4* op = (float4*)(Pout + (size_t)node * PST + part * 36);
#pragma unroll
    for (int q = 0; q < 9; ++q)
        op[q] = make_float4(res[4*q], res[4*q+1], res[4*q+2], res[4*q+3]);
}

// ---------------- weight transpose/pack ----------------
__global__ __launch_bounds__(256) void pack_kernel(
    const float* __restrict__ ew1, const float* __restrict__ ew2,
    const float* __restrict__ cw1,
    const float* __restrict__ nw1, const float* __restrict__ nw2,
    float* __restrict__ w1tp, float* __restrict__ w1rp, float* __restrict__ w2p,
    float* __restrict__ cw1t, float* __restrict__ nw1t, float* __restrict__ nw2t)
{
    const int stride = gridDim.x * 256;
    const int t0 = blockIdx.x * 256 + threadIdx.x;
    for (int idx = t0; idx < 3 * 132 * 16; idx += stride) {
        int d = idx / (132 * 16); int r = idx - d * 132 * 16; int o = r >> 4; int c = r & 15;
        int u = (o < 66) ? o : (o - 66);
        int cc = (o < 66) ? c : (16 + c);
        w1tp[idx] = ew1[(d * 33 + cc) * 66 + u];
    }
    for (int idx = t0; idx < 3 * 72; idx += stride) {
        int d = idx / 72; int o = idx - d * 72; int hh = o / 36; int uu = o - hh * 36;
        w1rp[idx] = (uu < 33) ? ew1[(d * 33 + 32) * 66 + hh * 33 + uu] : 0.0f;
    }
    for (int idx = t0; idx < 3 * 72 * 16; idx += stride) {
        int d = idx / (72 * 16); int r = idx - d * 72 * 16; int u = r >> 4; int v = r & 15;
        int hh = u / 36; int uu = u - hh * 36;
        w2p[idx] = (uu < 33) ? ew2[(d * 66 + hh * 33 + uu) * 16 + v] : 0.0f;
    }
    for (int idx = t0; idx < 3 * CH * 16; idx += stride) {
        int d = idx / (CH * 16); int r = idx - d * CH * 16; int t = r >> 4; int v = r & 15;
        cw1t[(d * CH + t) * 16 + v] = cw1[(d * 16 + v) * CH + t];
    }
    for (int idx = t0; idx < 3 * NHID * 32; idx += stride) {
        int d = idx / (NHID * 32); int r = idx - d * NHID * 32; int u = r >> 5; int c = r & 31;
        nw1t[(d * NHID + u) * 32 + c] = nw1[(d * 32 + c) * NHID + u];
    }
    for (int idx = t0; idx < 3 * 16 * 32; idx += stride) {
        int d = idx / (16 * 32); int r = idx - d * 16 * 32; int c = r >> 5; int u = r & 31;
        nw2t[(d * 16 + c) * 32 + u] = nw2[(d * 32 + u) * 16 + c];
    }
}

__device__ __forceinline__ void merge8(u32* a, const u32* bb) {
    u32 c[8];
#pragma unroll
    for (int t = 0; t < 8; ++t) c[t] = min(a[t], bb[7 - t]);
#define MCAS(x, y) { u32 mn = min(c[x], c[y]); u32 mx = max(c[x], c[y]); c[x] = mn; c[y] = mx; }
    MCAS(0, 4) MCAS(1, 5) MCAS(2, 6) MCAS(3, 7)
    MCAS(0, 2) MCAS(1, 3) MCAS(4, 6) MCAS(5, 7)
    MCAS(0, 1) MCAS(2, 3) MCAS(4, 5) MCAS(6, 7)
#undef MCAS
#pragma unroll
    for (int t = 0; t < 8; ++t) a[t] = c[t];
}

// ---------------- FUSED knn+layer for one d, 16 nodes/block -> 4 blocks/CU ----------------
// r13 post-mortem: grid=512 capped occupancy at 2 blocks/CU (20%); both phases
// latency-bound. 1024 blocks x 16 nodes doubles resident waves. kNN: 16 queries x
// 16 slices x 64 cands (unique-u32 keys => merge reshape bitwise-safe). Layer: r8's
// 1-node lane-swap body (verified). Cooperative launch NOT capture-safe (r12).
// 1e5 sentinel is load-bearing: do NOT length-clamp (r4/r5).
__global__ __launch_bounds__(256, 4) void fused_kernel(
    const int d,
    const float* __restrict__ coordsIn, float* __restrict__ coordsOut,
    const float* __restrict__ featsIn, float* __restrict__ featsOut,
    const float* __restrict__ Pbuf, float* __restrict__ PbufOut,
    int* __restrict__ idxbuf, const int* __restrict__ lengths,
    const float* __restrict__ w1rp, const float* __restrict__ w2p,
    const float* __restrict__ g_eb2,
    const float* __restrict__ cw1t, const float* __restrict__ g_cb1,
    const float* __restrict__ g_cw2, const float* __restrict__ g_cb2,
    const float* __restrict__ g_lng, const float* __restrict__ g_lnb,
    const float* __restrict__ nw1t, const float* __restrict__ g_nb1,
    const float* __restrict__ nw2t, const float* __restrict__ g_nb2,
    const float* __restrict__ w1tp_all, const float* __restrict__ g_eb1,
    const float* __restrict__ fw, const float* __restrict__ fb,
    float* __restrict__ gout)
{
    __shared__ __align__(16) char smem[25600];
    const int tid = threadIdx.x;
    const int lane = tid & 63;

    // ================= kNN phase: 16 queries, 16 slices x 64 candidates =================
    {
        float4* s_cand = (float4*)smem;                 // 16384 B
        u32* lst_base  = (u32*)(smem + 16384);          // 16*16*9*4 = 9216 B
        const int bk = blockIdx.x >> 6;                 // 64 blocks per batch
        const int i0 = (blockIdx.x & 63) << 4;          // 16 queries/block
        const int len = lengths[bk];
        const float* cb = coordsIn + (size_t)bk * SL * 3;
        for (int idx = tid; idx < SL; idx += 256) {
            const float* cp = cb + idx * 3;
            s_cand[idx] = make_float4(cp[0], cp[1], cp[2], 0.0f);
        }
        __syncthreads();

        const int q = tid & 15;
        const int s = tid >> 4;                          // slice 0..15
        const int i = i0 + q;
        const bool mi = i < len;
        const float4 qi = s_cand[i];
        const float xi = qi.x, yi = qi.y, zi = qi.z;

        u32 lst[8];
#pragma unroll
        for (int t = 0; t < 8; ++t) lst[t] = 0xFFFFFFFFu;

        const int jbase = s << 6;
#pragma unroll 4
        for (int jj = 0; jj < 64; ++jj) {
            const int j = jbase + jj;
            const float4 cj = s_cand[j];
            const float dx = xi - cj.x, dy = yi - cj.y, dz = zi - cj.z;
            const float dist = dx * dx + dy * dy + dz * dz;
            const int dij = j - i;
            const bool pm = mi && (j < len);
            const bool adjx = (dij == 1) | (dij == -1);
            float v = pm ? (adjx ? 0.0f : dist) : 1e5f;
            v = (dij == 0) ? -1.0f : v;
            u32 bits = __float_as_uint(v);
            bits ^= (u32)((int)bits >> 31) | 0x80000000u;
            const u32 key = (bits & 0xFFFFFC00u) | (u32)j;
#pragma unroll
            for (int p = 7; p >= 1; --p)
                lst[p] = min(max(key, lst[p - 1]), lst[p]);
            lst[0] = min(key, lst[0]);
        }
#pragma unroll
        for (int t = 0; t < 8; ++t) lst_base[(s * 16 + q) * 9 + t] = lst[t];
        __syncthreads();

        if (tid < 128) {
            const int p = tid >> 4, qq = tid & 15;
            u32 a[8], bb[8];
#pragma unroll
            for (int t = 0; t < 8; ++t) {
                a[t]  = lst_base[((2 * p) * 16 + qq) * 9 + t];
                bb[t] = lst_base[((2 * p + 1) * 16 + qq) * 9 + t];
            }
            merge8(a, bb);
#pragma unroll
            for (int t = 0; t < 8; ++t) lst_base[((2 * p) * 16 + qq) * 9 + t] = a[t];
        }
        __syncthreads();
        if (tid < 64) {
            const int p = tid >> 4, qq = tid & 15;
            u32 a[8], bb[8];
#pragma unroll
            for (int t = 0; t < 8; ++t) {
                a[t]  = lst_base[((4 * p) * 16 + qq) * 9 + t];
                bb[t] = lst_base[((4 * p + 2) * 16 + qq) * 9 + t];
            }
            merge8(a, bb);
#pragma unroll
            for (int t = 0; t < 8; ++t) lst_base[((4 * p) * 16 + qq) * 9 + t] = a[t];
        }
        __syncthreads();
        if (tid < 32) {
            const int p = tid >> 4, qq = tid & 15;
            u32 a[8], bb[8];
#pragma unroll
            for (int t = 0; t < 8; ++t) {
                a[t]  = lst_base[((8 * p) * 16 + qq) * 9 + t];
                bb[t] = lst_base[((8 * p + 4) * 16 + qq) * 9 + t];
            }
            merge8(a, bb);
#pragma unroll
            for (int t = 0; t < 8; ++t) lst_base[((8 * p) * 16 + qq) * 9 + t] = a[t];
        }
        __syncthreads();
        if (tid < 16) {
            const int qq = tid;
            u32 a[8], bb[8];
#pragma unroll
            for (int t = 0; t < 8; ++t) {
                a[t]  = lst_base[(0 * 16 + qq) * 9 + t];
                bb[t] = lst_base[(8 * 16 + qq) * 9 + t];
            }
            merge8(a, bb);
            const size_t node = (size_t)bk * SL + i0 + qq;
            int4 r0 = make_int4((int)(a[0] & 1023u), (int)(a[1] & 1023u), (int)(a[2] & 1023u), (int)(a[3] & 1023u));
            int4 r1 = make_int4((int)(a[4] & 1023u), (int)(a[5] & 1023u), (int)(a[6] & 1023u), (int)(a[7] & 1023u));
            ((int4*)idxbuf)[node * 2 + 0] = r0;
            ((int4*)idxbuf)[node * 2 + 1] = r1;
        }
    }
    __syncthreads();   // knn LDS readers done; this block's idxbuf rows visible (same L1)

    // ================= layer phase (r8 1-node lane-swap body) =================
    {
        float* s_w2e  = (float*)(smem);
        float* s_cw1  = (float*)(smem + 4608);
        float* s_nw1  = (float*)(smem + 8704);
        float* s_nw2  = (float*)(smem + 13312);
        float* s_w1r  = (float*)(smem + 15616);
        float* s_cw2v = (float*)(smem + 15904);
        float* s_cb1  = (float*)(smem + 16160);
        float* s_eb2  = (float*)(smem + 16416);
        float* s_lng  = (float*)(smem + 16480);
        float* s_lnb  = (float*)(smem + 16544);
        float* s_nb1  = (float*)(smem + 16608);
        float* s_nb2  = (float*)(smem + 16736);
        float* s_cb2  = (float*)(smem + 16800);

        for (int t = tid; t < 72 * 16; t += 256) s_w2e[t] = w2p[d * 72 * 16 + t];
        for (int t = tid; t < CH * 16; t += 256) s_cw1[t] = cw1t[d * CH * 16 + t];
        for (int t = tid; t < NHID * 32; t += 256) s_nw1[(t >> 5) * 36 + (t & 31)] = nw1t[d * NHID * 32 + t];
        for (int t = tid; t < 16 * 32; t += 256) s_nw2[(t >> 5) * 36 + (t & 31)] = nw2t[d * 16 * 32 + t];
        if (tid < 72) s_w1r[tid] = w1rp[d * 72 + tid];
        if (tid < CH) { s_cw2v[tid] = g_cw2[d * CH + tid]; s_cb1[tid] = g_cb1[d * CH + tid]; }
        if (tid < 16) {
            s_eb2[tid] = g_eb2[d * 16 + tid];
            s_lng[tid] = g_lng[d * 16 + tid];
            s_lnb[tid] = g_lnb[d * 16 + tid];
            s_nb2[tid] = g_nb2[d * 16 + tid];
        }
        if (tid < 32) s_nb1[tid] = g_nb1[d * 32 + tid];
        if (tid == 0) s_cb2[0] = g_cb2[d];

        const int h = (lane >> 3) & 1;
        const int k = lane & 7;
        const int sub = lane & 15;
        const int n = blockIdx.x * 16 + (tid >> 4);
        const int b = n >> 10;
        const int len = lengths[b];
        const int j = idxbuf[n * 8 + k];
        const bool em = ((n & 1023) < len) && (j < len);

        float ci[3], rel[3];
        {
            const float* cp = coordsIn + (size_t)n * 3;
            const float* cq = coordsIn + ((size_t)b * SL + j) * 3;
            ci[0] = cp[0]; ci[1] = cp[1]; ci[2] = cp[2];
            rel[0] = ci[0] - cq[0]; rel[1] = ci[1] - cq[1]; rel[2] = ci[2] - cq[2];
        }
        const float rd = fmaf(rel[0], rel[0], fmaf(rel[1], rel[1], rel[2] * rel[2]));

        const int ub = h * 36;
        const float* PiP = Pbuf + (size_t)n * PST + ub;
        const float* PjP = Pbuf + ((size_t)b * SL + j) * PST + 72 + ub;
        float4 pa = *(const float4*)PiP;
        float4 pb = *(const float4*)PjP;

        __syncthreads();   // weights staged

        float macc[16];
#pragma unroll
        for (int v = 0; v < 16; ++v) macc[v] = h ? 0.0f : s_eb2[v];
#pragma unroll
        for (int c4 = 0; c4 < 9; ++c4) {
            float4 na, nb;
            if (c4 < 8) {
                na = *(const float4*)(PiP + 4 * (c4 + 1));
                nb = *(const float4*)(PjP + 4 * (c4 + 1));
            }
            const int u0 = ub + c4 * 4;
            const float4 w1r4 = *(const float4*)&s_w1r[u0];
            const float hu0 = silu_f(fmaf(rd, w1r4.x, pa.x + pb.x));
            const float hu1 = silu_f(fmaf(rd, w1r4.y, pa.y + pb.y));
            const float hu2 = silu_f(fmaf(rd, w1r4.z, pa.z + pb.z));
            const float hu3 = silu_f(fmaf(rd, w1r4.w, pa.w + pb.w));
            const float* w2r = &s_w2e[u0 * 16];
#pragma unroll
            for (int v = 0; v < 16; ++v) {
                float m0 = fmaf(hu0, w2r[v], macc[v]);
                float m1 = fmaf(hu1, w2r[16 + v], m0);
                float m2 = fmaf(hu2, w2r[32 + v], m1);
                macc[v] = fmaf(hu3, w2r[48 + v], m2);
            }
            if (c4 < 8) { pa = na; pb = nb; }
        }

        // combine halves in-wave (partner = lane^8): macc becomes mm in place
#pragma unroll
        for (int v = 0; v < 16; ++v)
            macc[v] = silu_f(macc[v] + __shfl_xor(macc[v], 8, 64));

        const int tb = h * 32;
        float wa = 0.f;
#pragma unroll 4
        for (int tt = 0; tt < 32; ++tt) {
            const float* cr = &s_cw1[(tb + tt) * 16];
            float a0 = s_cb1[tb + tt], a1 = 0.f;
#pragma unroll
            for (int v = 0; v < 16; v += 2) {
                a0 = fmaf(macc[v], cr[v], a0);
                a1 = fmaf(macc[v + 1], cr[v + 1], a1);
            }
            wa = fmaf(silu_f(a0 + a1), s_cw2v[tb + tt], wa);
        }
        const float wao = __shfl_xor(wa, 8, 64);
        const float we = em ? (wa + wao + s_cb2[0]) : 0.f;

        float wr0 = we * rel[0], wr1 = we * rel[1], wr2 = we * rel[2];
#pragma unroll
        for (int s = 1; s < 8; s <<= 1) {
            wr0 += __shfl_xor(wr0, s, 64);
            wr1 += __shfl_xor(wr1, s, 64);
            wr2 += __shfl_xor(wr2, s, 64);
        }
        if ((lane & 15) == 0) {
            coordsOut[(size_t)n * 3 + 0] = ci[0] + wr0;
            coordsOut[(size_t)n * 3 + 1] = ci[1] + wr1;
            coordsOut[(size_t)n * 3 + 2] = ci[2] + wr2;
        }

        // m_i in place
#pragma unroll
        for (int v = 0; v < 16; ++v) {
            macc[v] = em ? macc[v] : 0.f;
#pragma unroll
            for (int s = 1; s < 8; s <<= 1)
                macc[v] += __shfl_xor(macc[v], s, 64);
        }
        // macc now holds m_i.

        float fi[16];
        {
            const float4* pp = (const float4*)(featsIn + (size_t)n * DIM);
            float4 a0 = pp[0], a1 = pp[1], a2 = pp[2], a3 = pp[3];
            fi[0]=a0.x; fi[1]=a0.y; fi[2]=a0.z; fi[3]=a0.w;
            fi[4]=a1.x; fi[5]=a1.y; fi[6]=a1.z; fi[7]=a1.w;
            fi[8]=a2.x; fi[9]=a2.y; fi[10]=a2.z; fi[11]=a2.w;
            fi[12]=a3.x; fi[13]=a3.y; fi[14]=a3.z; fi[15]=a3.w;
        }
        const float fiSub = featsIn[(size_t)n * DIM + sub];   // residual channel

        // LayerNorm: fi becomes nn in place
        {
            float mu = 0.f;
#pragma unroll
            for (int c = 0; c < 16; ++c) mu += fi[c];
            mu *= 0.0625f;
            float var = 0.f;
#pragma unroll
            for (int c = 0; c < 16; ++c) { const float dd = fi[c] - mu; var = fmaf(dd, dd, var); }
            var *= 0.0625f;
            const float rs = rsqrtf(var + LN_EPS);
#pragma unroll
            for (int c = 0; c < 16; ++c) fi[c] = fmaf((fi[c] - mu) * rs, s_lng[c], s_lnb[c]);
        }

        float nh[2];
#pragma unroll
        for (int q2 = 0; q2 < 2; ++q2) {
            const int u = sub * 2 + q2;
            const float* nr = &s_nw1[u * 36];
            float a0 = s_nb1[u], a1 = 0.f;
#pragma unroll
            for (int c = 0; c < 16; c += 2) {
                a0 = fmaf(fi[c], nr[c], a0);
                a1 = fmaf(fi[c + 1], nr[c + 1], a1);
            }
#pragma unroll
            for (int v = 0; v < 16; v += 2) {
                a0 = fmaf(macc[v], nr[16 + v], a0);
                a1 = fmaf(macc[v + 1], nr[16 + v + 1], a1);
            }
            nh[q2] = silu_f(a0 + a1);
        }

        const int nbase = lane & ~15;
        const float* w2c = &s_nw2[sub * 36];
        float o0 = s_nb2[sub];
#pragma unroll
        for (int u = 0; u < 32; ++u) {
            const float v = __shfl(nh[u & 1], nbase + (u >> 1), 64);
            o0 = fmaf(v, w2c[u], o0);
        }
        const float fo = fiSub + o0;
        featsOut[(size_t)n * DIM + sub] = fo;

        // gather new feats row (phi for d<2; final for d==2)
        float fr[16];
#pragma unroll
        for (int c = 0; c < 16; ++c) fr[c] = __shfl(fo, nbase + c, 64);

        if (d < 2) {
            const float* wbase = w1tp_all + (d + 1) * 132 * 16;
            const float* bbase = g_eb1 + (d + 1) * 66;
            float* Pout = PbufOut + (size_t)n * PST;
#pragma unroll
            for (int q2 = 0; q2 < 9; ++q2) {
                const int col = sub + (q2 << 4);
                const int ch = (col >= 108) ? 3 : (col >= 72) ? 2 : (col >= 36) ? 1 : 0;
                const int uu = col - ch * 36;
                const bool valid = uu < 33;
                const int u = ((ch & 1) ? 33 : 0) + uu;
                const int uc = valid ? u : 0;
                const int widx = valid ? ((ch < 2) ? u : 66 + u) : 0;
                float a0 = (valid && ch < 2) ? bbase[uc] : 0.0f;
                float a1 = 0.f, a2 = 0.f, a3 = 0.f;
                const float* wr = wbase + widx * 16;
#pragma unroll
                for (int cc = 0; cc < 16; cc += 4) {
                    a0 = fmaf(fr[cc + 0], wr[cc + 0], a0);
                    a1 = fmaf(fr[cc + 1], wr[cc + 1], a1);
                    a2 = fmaf(fr[cc + 2], wr[cc + 2], a2);
                    a3 = fmaf(fr[cc + 3], wr[cc + 3], a3);
                }
                Pout[col] = valid ? ((a0 + a1) + (a2 + a3)) : 0.0f;
            }
        } else {
            // fused final projection: lanes sub<3 compute output channel sub
            if (sub < 3) {
                float acc = fb[sub];
#pragma unroll
                for (int c = 0; c < 16; ++c)
                    acc = fmaf(fr[c], fw[c * 3 + sub], acc);
                gout[(size_t)n * 3 + sub] = acc;
            }
        }
    }
}

extern "C" void kernel_launch(void* const* d_in, const int* in_sizes, int n_in,
                              void* d_out, int out_size, void* d_ws, size_t ws_size,
                              hipStream_t stream) {
    const float* coords    = (const float*)d_in[0];
    const int*   residues  = (const int*)d_in[1];
    const int*   lengths   = (const int*)d_in[2];
    const float* token_emb = (const float*)d_in[3];
    const float* pos_emb   = (const float*)d_in[4];
    const float* ew1 = (const float*)d_in[5];
    const float* eb1 = (const float*)d_in[6];
    const float* ew2 = (const float*)d_in[7];
    const float* eb2 = (const float*)d_in[8];
    const float* cw1 = (const float*)d_in[9];
    const float* cb1 = (const float*)d_in[10];
    const float* cw2 = (const float*)d_in[11];
    const float* cb2 = (const float*)d_in[12];
    const float* lng = (const float*)d_in[13];
    const float* lnb = (const float*)d_in[14];
    const float* nw1 = (const float*)d_in[15];
    const float* nb1 = (const float*)d_in[16];
    const float* nw2 = (const float*)d_in[17];
    const float* nb2 = (const float*)d_in[18];
    const float* fw  = (const float*)d_in[19];
    const float* fb  = (const float*)d_in[20];

    float* ws = (float*)d_ws;
    float* coordsA = ws;
    float* coordsB = coordsA + NB * SL * 3;
    float* featsA  = coordsB + NB * SL * 3;
    float* featsB  = featsA + NB * SL * DIM;
    int*   idxbuf  = (int*)(featsB + NB * SL * DIM);
    float* w1tp = (float*)(idxbuf + NB * SL * KNN);     // 3*132*16
    float* w1rp = w1tp + 3 * 132 * 16;                  // 3*72
    float* w2p  = w1rp + 3 * 72;                        // 3*72*16
    float* cw1t = w2p + 3 * 72 * 16;                    // 3*64*16
    float* nw1t = cw1t + 3 * CH * 16;                   // 3*32*32
    float* nw2t = nw1t + 3 * NHID * 32;                 // 3*16*32
    float* PbufA = nw2t + 3 * 16 * 32;                  // 16384*144
    float* PbufB = PbufA + (size_t)NB * SL * PST;       // 16384*144
    float* gout  = (float*)d_out;

    pack_kernel<<<32, 256, 0, stream>>>(ew1, ew2, cw1, nw1, nw2, w1tp, w1rp, w2p, cw1t, nw1t, nw2t);
    init_kernel<<<NB * SL * 4 / 256, 256, 0, stream>>>(coords, residues, token_emb, pos_emb,
                                                        w1tp, eb1, coordsA, featsA, PbufA);

    float* cIn = coordsA; float* cOut = coordsB;
    float* fIn = featsA;  float* fOut = featsB;
    float* pIn = PbufA;   float* pOut = PbufB;
    for (int d = 0; d < 3; ++d) {
        fused_kernel<<<NB * SL / 16, 256, 0, stream>>>(d, cIn, cOut, fIn, fOut, pIn, pOut,
            idxbuf, lengths,
            w1rp, w2p, eb2, cw1t, cb1, cw2, cb2, lng, lnb, nw1t, nb1, nw2t, nb2,
            w1tp, eb1, fw, fb, gout);
        float* t;
        t = cIn; cIn = cOut; cOut = t;
        t = fIn; fIn = fOut; fOut = t;
        t = pIn; pIn = pOut; pOut = t;
    }
}